// Round 8
// baseline (397.113 us; speedup 1.0000x reference)
//
#include <hip/hip_runtime.h>
#include <hip/hip_bf16.h>
#include <math.h>

// Problem constants (from reference)
constexpr int N = 100000;    // nodes
constexpr int E = 3200000;   // edges
constexpr int FIN = 128, H1 = 64, H2 = 32, COUT = 2;

// Bucketing: 256 nodes per bucket, fixed-capacity slices
constexpr int BUK_SHIFT = 8;
constexpr int BUK_NODES = 256;                         // 1 << BUK_SHIFT
constexpr int NBUK = (N + BUK_NODES - 1) / BUK_NODES;  // 391
constexpr int CAP = 10240;            // slice capacity; mean fill 8192, sigma~90
constexpr int MS_TPB = 1024;
constexpr int MS_EPT = 12;                             // edges per thread
constexpr int CHUNK = MS_TPB * MS_EPT;                 // 12288
constexpr int MS_WGS = (E + CHUNK - 1) / CHUNK;        // 261

// ---------------- init: gcursor[b] = b*CAP ----------------
__global__ void k_initcur(int* __restrict__ gcursor) {
    int i = blockIdx.x * blockDim.x + threadIdx.x;
    if (i < NBUK) gcursor[i] = i * CAP;
}

// ---------------- multisplit into fixed-capacity bucket slices ----------------
// packed entry: src (17 bits) | local_node (8 bits) << 17
__global__ __launch_bounds__(MS_TPB)
void k_mslice(const int* __restrict__ src, const int* __restrict__ dst,
              int* __restrict__ gcursor, unsigned* __restrict__ ebuf) {
    __shared__ int cnt[NBUK];
    __shared__ int base[NBUK];
    const int t = threadIdx.x;
    for (int i = t; i < NBUK; i += MS_TPB) cnt[i] = 0;
    __syncthreads();
    const int e0 = blockIdx.x * CHUNK;

    int rb[MS_EPT];       // bucket (or -1)
    unsigned rv[MS_EPT];  // packed value
#pragma unroll
    for (int j = 0; j < MS_EPT; ++j) {
        int e = e0 + j * MS_TPB + t;
        if (e < E) {
            int d = dst[e];
            int b = d >> BUK_SHIFT;
            rb[j] = b;
            rv[j] = (unsigned)src[e] | ((unsigned)(d & (BUK_NODES - 1)) << 17);
            atomicAdd(&cnt[b], 1);
        } else {
            rb[j] = -1; rv[j] = 0;
        }
    }
    __syncthreads();
    for (int i = t; i < NBUK; i += MS_TPB) {
        int c = cnt[i];
        base[i] = c ? atomicAdd(&gcursor[i], c) : 0;
    }
    __syncthreads();
    for (int i = t; i < NBUK; i += MS_TPB) cnt[i] = 0;
    __syncthreads();
#pragma unroll
    for (int j = 0; j < MS_EPT; ++j) {
        int b = rb[j];
        if (b >= 0) {
            int r = atomicAdd(&cnt[b], 1);
            int p = base[b] + r;
            if (p < (b + 1) * CAP) ebuf[p] = rv[j];   // overflow guard (statistically impossible)
        }
    }
}

// ---------------- scan bucket fills -> compact csr bases ----------------
__global__ __launch_bounds__(512)
void k_bscan(const int* __restrict__ gcursor, int* __restrict__ bbase,
             int* __restrict__ rowptr) {
    __shared__ int sm[512];
    const int t = threadIdx.x;
    int v = (t < NBUK) ? (gcursor[t] - t * CAP) : 0;
    sm[t] = v;
    __syncthreads();
    for (int off = 1; off < 512; off <<= 1) {
        int cur = sm[t];
        int add = (t >= off) ? sm[t - off] : 0;
        __syncthreads();
        sm[t] = cur + add;
        __syncthreads();
    }
    if (t < NBUK) bbase[t] = sm[t] - v;   // exclusive
    if (t == 0) { bbase[NBUK] = E; rowptr[N] = E; }
}

// ---------------- per-bucket CSR build, slice sorted in LDS ----------------
__global__ __launch_bounds__(256)
void k_build(const int* __restrict__ gcursor, const int* __restrict__ bbase,
             const unsigned* __restrict__ ebuf, int* __restrict__ rowptr,
             float* __restrict__ dinv, int* __restrict__ csr_src) {
    __shared__ unsigned ent[CAP];
    __shared__ int cnt[BUK_NODES];
    __shared__ int sm[BUK_NODES];
    __shared__ int cur[BUK_NODES];
    const int b = blockIdx.x;
    const int t = threadIdx.x;
    const int fill = gcursor[b] - b * CAP;
    const int gsrc = b * CAP;
    const int gdst = bbase[b];

    cnt[t] = 0;
    __syncthreads();
    for (int j = t; j < fill; j += 256) {
        unsigned v = ebuf[gsrc + j];
        ent[j] = v;
        atomicAdd(&cnt[v >> 17], 1);
    }
    __syncthreads();
    sm[t] = cnt[t];
    __syncthreads();
    for (int off = 1; off < BUK_NODES; off <<= 1) {
        int cv = sm[t];
        int add = (t >= off) ? sm[t - off] : 0;
        __syncthreads();
        sm[t] = cv + add;
        __syncthreads();
    }
    {
        int ex = sm[t] - cnt[t];
        cur[t] = gdst + ex;
        int node = (b << BUK_SHIFT) + t;
        if (node < N) {
            rowptr[node] = gdst + ex;
            dinv[node] = rsqrtf((float)cnt[t] + 1.0f);   // self-loop included
        }
    }
    __syncthreads();
    for (int j = t; j < fill; j += 256) {
        unsigned v = ent[j];
        int p = atomicAdd(&cur[v >> 17], 1);
        csr_src[p] = (int)(v & 0x1FFFFu);
    }
}

// ---------------- register-tiled GEMM + dinv scale, bf16 output ----------------
template<int FI, int FO>
__global__ __launch_bounds__(256)
void k_gemm_tile_bf(const float* __restrict__ h, const float* __restrict__ Wg,
                    const float* __restrict__ dinv, __hip_bfloat16* __restrict__ y) {
    constexpr int TX  = FO / 4;        // 16 (FO=64) or 8 (FO=32)
    constexpr int TY  = 256 / TX;      // 16 or 32
    constexpr int RPT = 64 / TY;       // 4 or 2
    constexpr int XS  = 68;            // padded row stride (floats)
    constexpr int KQ  = FI / 4;        // float4s per input row

    __shared__ float xsT[FI][XS];

    const int tid = threadIdx.x;
    const int tx = tid % TX;
    const int ty = tid / TX;
    const int row0 = blockIdx.x * 64;

    for (int idx = tid; idx < 64 * KQ; idx += 256) {
        int g   = idx / 8;
        int rlo = idx % 8;
        int k4  = g % KQ;
        int rhi = g / KQ;
        int r   = rlo + 8 * rhi;
        int row = row0 + r;
        float4 v = make_float4(0.f, 0.f, 0.f, 0.f);
        if (row < N) v = *(const float4*)(h + (size_t)row * FI + 4 * k4);
        xsT[4 * k4 + 0][r] = v.x;
        xsT[4 * k4 + 1][r] = v.y;
        xsT[4 * k4 + 2][r] = v.z;
        xsT[4 * k4 + 3][r] = v.w;
    }
    __syncthreads();

    float acc[RPT][4];
#pragma unroll
    for (int i = 0; i < RPT; ++i)
#pragma unroll
        for (int c = 0; c < 4; ++c) acc[i][c] = 0.0f;

#pragma unroll 4
    for (int k = 0; k < FI; ++k) {
        const float4 wv = *(const float4*)(Wg + (size_t)k * FO + 4 * tx);
        float xv[RPT];
        if constexpr (RPT == 4) {
            float4 t = *(const float4*)&xsT[k][4 * ty];
            xv[0] = t.x; xv[1] = t.y; xv[2] = t.z; xv[3] = t.w;
        } else {
            float2 t = *(const float2*)&xsT[k][2 * ty];
            xv[0] = t.x; xv[1] = t.y;
        }
#pragma unroll
        for (int i = 0; i < RPT; ++i) {
            acc[i][0] = fmaf(xv[i], wv.x, acc[i][0]);
            acc[i][1] = fmaf(xv[i], wv.y, acc[i][1]);
            acc[i][2] = fmaf(xv[i], wv.z, acc[i][2]);
            acc[i][3] = fmaf(xv[i], wv.w, acc[i][3]);
        }
    }

#pragma unroll
    for (int i = 0; i < RPT; ++i) {
        int row = row0 + ty * RPT + i;
        if (row >= N) continue;
        float di = dinv[row];
        auto cvt = [](float f) -> unsigned short {
            __hip_bfloat16 b = __float2bfloat16(f);
            return *reinterpret_cast<unsigned short*>(&b);
        };
        ushort4 pk;
        pk.x = cvt(di * acc[i][0]);
        pk.y = cvt(di * acc[i][1]);
        pk.z = cvt(di * acc[i][2]);
        pk.w = cvt(di * acc[i][3]);
        *(ushort4*)&y[(size_t)row * FO + 4 * tx] = pk;
    }
}

// ---------------- fused GEMM + dinv scale, fp32 output (layer 3, tiny) ----------------
template<int FI, int FO, int ROWS>
__global__ __launch_bounds__(FO * ROWS)
void k_gemm_scale(const float* __restrict__ h, const float* __restrict__ W,
                  const float* __restrict__ dinv, float* __restrict__ y) {
    __shared__ float xs[ROWS][FI];
    const int j = threadIdx.x;
    const int r = threadIdx.y;
    const int row0 = blockIdx.x * ROWS;
    const int tid = r * FO + j;
    constexpr int NT = FO * ROWS;
    for (int t = tid; t < ROWS * FI; t += NT) {
        int rr = t / FI, kk = t % FI;
        int row = row0 + rr;
        xs[rr][kk] = (row < N) ? h[(size_t)row * FI + kk] : 0.0f;
    }
    __syncthreads();
    const int row = row0 + r;
    if (row >= N) return;
    float acc = 0.0f;
#pragma unroll
    for (int k = 0; k < FI; ++k)
        acc = fmaf(xs[r][k], W[k * FO + j], acc);
    y[(size_t)row * FO + j] = dinv[row] * acc;
}

// ---------------- layer-1 aggregate, XCD feature-sharded (F=64) ----------------
// Each y1 row = 128 B = two 64-B lines. half = blockIdx&1 selects which line;
// with round-robin block->XCD dispatch (XCD = blockIdx%8), even XCDs only touch
// even-offset lines and odd XCDs odd lines: per-XCD L2 working set 12.8->6.4 MB,
// each line fetched by <=4 XCDs instead of 8.
__global__ __launch_bounds__(256)
void k_aggregate1_bf(const int* __restrict__ rowptr, const int* __restrict__ csr_src,
                     const __hip_bfloat16* __restrict__ y, const float* __restrict__ dinv,
                     const float* __restrict__ b, float* __restrict__ out) {
    constexpr int LPN = 16;            // lanes per node (16 feat-pairs = 32 feats = 64 B)
    constexpr int NPB = 16;            // nodes per block
    const int g = blockIdx.x & 1;      // feature half (== XCD parity under %8 dispatch)
    const int nb = (int)(blockIdx.x >> 1);
    const int fp = threadIdx.x;        // 0..15 feat-pair within half
    const int n = nb * NPB + threadIdx.y;
    if (n >= N) return;
    const unsigned* yw = (const unsigned*)y;   // 32 bf16x2 words per row
    const int wo = g * 16 + fp;                // word offset within row

    auto load2 = [&](int s) -> float2 {
        unsigned u = yw[(size_t)s * 32 + wo];
        float2 v;
        v.x = __uint_as_float(u << 16);
        v.y = __uint_as_float(u & 0xffff0000u);
        return v;
    };

    float2 acc = load2(n);   // self-loop
    const int j0 = rowptr[n], j1 = rowptr[n + 1];
    int j = j0;
    for (; j + 8 <= j1; j += 8) {
        int s0 = csr_src[j],     s1 = csr_src[j + 1], s2 = csr_src[j + 2], s3 = csr_src[j + 3];
        int s4 = csr_src[j + 4], s5 = csr_src[j + 5], s6 = csr_src[j + 6], s7 = csr_src[j + 7];
        float2 v0 = load2(s0), v1 = load2(s1), v2 = load2(s2), v3 = load2(s3);
        float2 v4 = load2(s4), v5 = load2(s5), v6 = load2(s6), v7 = load2(s7);
        acc.x += ((v0.x + v1.x) + (v2.x + v3.x)) + ((v4.x + v5.x) + (v6.x + v7.x));
        acc.y += ((v0.y + v1.y) + (v2.y + v3.y)) + ((v4.y + v5.y) + (v6.y + v7.y));
    }
    for (; j < j1; ++j) {
        float2 v = load2(csr_src[j]);
        acc.x += v.x; acc.y += v.y;
    }
    const float di = dinv[n];
    const int f0 = 2 * wo;             // global feature index
    float o0 = fmaxf(fmaf(di, acc.x, b[f0]), 0.0f);
    float o1 = fmaxf(fmaf(di, acc.y, b[f0 + 1]), 0.0f);
    float2 res; res.x = o0; res.y = o1;
    *(float2*)&out[(size_t)n * H1 + f0] = res;
}

// ---------------- CSR aggregate (bf16 gather) + fused epilogue (layer 2) ----------------
template<int F, bool RELU>
__global__ __launch_bounds__(256)
void k_aggregate_bf(const int* __restrict__ rowptr, const int* __restrict__ csr_src,
                    const __hip_bfloat16* __restrict__ y, const float* __restrict__ dinv,
                    const float* __restrict__ b, float* __restrict__ out) {
    constexpr int LPN = F / 2;         // lanes per node
    constexpr int NPB = 256 / LPN;     // nodes per block
    const int fp = threadIdx.x;        // feature-pair index
    const int n = blockIdx.x * NPB + threadIdx.y;
    if (n >= N) return;
    const unsigned* yw = (const unsigned*)y;

    auto load2 = [&](int s) -> float2 {
        unsigned u = yw[(size_t)s * LPN + fp];
        float2 v;
        v.x = __uint_as_float(u << 16);
        v.y = __uint_as_float(u & 0xffff0000u);
        return v;
    };

    float2 acc = load2(n);   // self-loop
    const int j0 = rowptr[n], j1 = rowptr[n + 1];
    int j = j0;
    for (; j + 8 <= j1; j += 8) {
        int s0 = csr_src[j],     s1 = csr_src[j + 1], s2 = csr_src[j + 2], s3 = csr_src[j + 3];
        int s4 = csr_src[j + 4], s5 = csr_src[j + 5], s6 = csr_src[j + 6], s7 = csr_src[j + 7];
        float2 v0 = load2(s0), v1 = load2(s1), v2 = load2(s2), v3 = load2(s3);
        float2 v4 = load2(s4), v5 = load2(s5), v6 = load2(s6), v7 = load2(s7);
        acc.x += ((v0.x + v1.x) + (v2.x + v3.x)) + ((v4.x + v5.x) + (v6.x + v7.x));
        acc.y += ((v0.y + v1.y) + (v2.y + v3.y)) + ((v4.y + v5.y) + (v6.y + v7.y));
    }
    for (; j < j1; ++j) {
        float2 v = load2(csr_src[j]);
        acc.x += v.x; acc.y += v.y;
    }
    const float di = dinv[n];
    float o0 = fmaf(di, acc.x, b[2 * fp]);
    float o1 = fmaf(di, acc.y, b[2 * fp + 1]);
    if (RELU) { o0 = fmaxf(o0, 0.0f); o1 = fmaxf(o1, 0.0f); }
    float2 res; res.x = o0; res.y = o1;
    *(float2*)&out[(size_t)n * F + 2 * fp] = res;
}

// ---------------- layer 3 aggregate + log_softmax (2 classes) ----------------
__global__ __launch_bounds__(256)
void k_final(const int* __restrict__ rowptr, const int* __restrict__ csr_src,
             const float* __restrict__ y, const float* __restrict__ dinv,
             const float* __restrict__ b, float* __restrict__ out) {
    const int c = threadIdx.x;                       // class 0/1
    const int n = blockIdx.x * 128 + threadIdx.y;    // node
    float z = 0.0f;
    if (n < N) {
        const int j0 = rowptr[n], j1 = rowptr[n + 1];
        float acc = y[2 * n + c];
        int j = j0;
        for (; j + 4 <= j1; j += 4) {
            int s0 = csr_src[j], s1 = csr_src[j + 1], s2 = csr_src[j + 2], s3 = csr_src[j + 3];
            float a0 = y[2 * s0 + c], a1 = y[2 * s1 + c];
            float a2 = y[2 * s2 + c], a3 = y[2 * s3 + c];
            acc += (a0 + a1) + (a2 + a3);
        }
        for (; j < j1; ++j) acc += y[2 * csr_src[j] + c];
        z = fmaf(dinv[n], acc, b[c]);
    }
    float zo = __shfl_xor(z, 1);
    if (n < N) {
        float m = fmaxf(z, zo);
        float lse = m + logf(expf(z - m) + expf(zo - m));
        out[2 * n + c] = z - lse;
    }
}

extern "C" void kernel_launch(void* const* d_in, const int* in_sizes, int n_in,
                              void* d_out, int out_size, void* d_ws, size_t ws_size,
                              hipStream_t stream) {
    const float* x   = (const float*)d_in[0];
    const int*   ei  = (const int*)d_in[1];
    const float* W1  = (const float*)d_in[2];
    const float* b1  = (const float*)d_in[3];
    const float* W2  = (const float*)d_in[4];
    const float* b2  = (const float*)d_in[5];
    const float* W3  = (const float*)d_in[6];
    const float* b3  = (const float*)d_in[7];
    float* out = (float*)d_out;

    const int* src = ei;
    const int* dst = ei + E;

    // workspace layout
    char* p = (char*)d_ws;
    int*   rowptr  = (int*)p;   p += (size_t)(N + 1) * 4;
    float* dinv    = (float*)p; p += (size_t)N * 4;
    int*   gcursor = (int*)p;   p += (size_t)NBUK * 4;
    int*   bbase   = (int*)p;   p += (size_t)(NBUK + 1) * 4;
    int*   csr_src = (int*)p;   p += (size_t)E * 4;
    char*  bufA    = p;         p += (size_t)N * 64 * 4;   // 25.6 MB scratch
    char*  bufB    = p;         p += (size_t)N * 64 * 4;   // 25.6 MB scratch

    unsigned*       ebuf  = (unsigned*)bufA;           // NBUK*CAP*4 = 16 MB; dead after k_build
    __hip_bfloat16* y1    = (__hip_bfloat16*)bufA;     // N*64*2 B (after ebuf dead)
    float*          h1    = (float*)bufB;              // N*64*4 B
    __hip_bfloat16* y2    = (__hip_bfloat16*)bufA;     // N*32*2 B (y1 dead)
    float*          h2    = (float*)(bufA + (size_t)N * H2 * 2);  // N*32*4 B
    float*          y3    = (float*)bufB;              // N*2*4 B (h1 dead)

    // ---- CSR build ----
    k_initcur<<<(NBUK + 255) / 256, 256, 0, stream>>>(gcursor);
    k_mslice <<<MS_WGS, MS_TPB, 0, stream>>>(src, dst, gcursor, ebuf);
    k_bscan  <<<1, 512, 0, stream>>>(gcursor, bbase, rowptr);
    k_build  <<<NBUK, 256, 0, stream>>>(gcursor, bbase, ebuf, rowptr, dinv, csr_src);

    // ---- layer 1: 128 -> 64 ----
    k_gemm_tile_bf<FIN, H1><<<(N + 63) / 64, 256, 0, stream>>>(x, W1, dinv, y1);
    k_aggregate1_bf<<<2 * ((N + 15) / 16), dim3(16, 16), 0, stream>>>(rowptr, csr_src, y1, dinv, b1, h1);

    // ---- layer 2: 64 -> 32 ----
    k_gemm_tile_bf<H1, H2><<<(N + 63) / 64, 256, 0, stream>>>(h1, W2, dinv, y2);
    k_aggregate_bf<H2, true><<<(N + 15) / 16, dim3(16, 16), 0, stream>>>(rowptr, csr_src, y2, dinv, b2, h2);

    // ---- layer 3: 32 -> 2 + log_softmax ----
    k_gemm_scale<H2, COUT, 128><<<(N + 127) / 128, dim3(COUT, 128), 0, stream>>>(h2, W3, dinv, y3);
    k_final<<<(N + 127) / 128, dim3(2, 128), 0, stream>>>(rowptr, csr_src, y3, dinv, b3, out);
}